// Round 9
// baseline (2857.998 us; speedup 1.0000x reference)
//
#include <hip/hip_runtime.h>

// ---------------------------------------------------------------------------
// GenesisBlock: x(8192x2048 fp32) -> z = x @ tq(W_syn)^T (f32)
//   -> top-k(819)/row threshold, hidden = relu-masked (bf16)
//   -> out = hidden @ tq(W_out)^T -> LN(x + out) -> FP32 out
//
// R13: XCD swizzle REVERTED (R12: FETCH 138->400MB, GEMM1 233->246us —
// remap destroyed default-dispatch locality; don't fight the dispatcher
// blind). GEMM1 = proven 128^2 TWO (233us). GEMM2 = 128^2 split-K=4.
// topk: pass-0 LDS histogram now uses wave-ballot aggregation (keys
// concentrate in ~20-40 sign/exponent bins -> naive atomics serialize
// up to 64-way intra-wave; leader-adds-popcount instead).
// ---------------------------------------------------------------------------

typedef __attribute__((ext_vector_type(8))) short short8;
typedef __attribute__((ext_vector_type(4))) float f32x4;

__device__ __forceinline__ float bf2f(unsigned h) {
    return __uint_as_float(h << 16);
}
__device__ __forceinline__ unsigned f2bf(float f) {
    unsigned u = __float_as_uint(f);
    return (u + 0x7fffu + ((u >> 16) & 1u)) >> 16;  // RNE
}

// async global->LDS, 16B per lane; lds base must be wave-uniform, lane l
// deposits at base + l*16B (linear, lane-ordered).
typedef __attribute__((address_space(1))) const void gq_void;
typedef __attribute__((address_space(3))) void ls_void;
__device__ __forceinline__ void gload16(const void* g, void* l) {
    __builtin_amdgcn_global_load_lds((gq_void*)g, (ls_void*)l, 16, 0, 0);
}

// ---------------------------------------------------------------------------
__global__ __launch_bounds__(64) void init_detect(float* sc, const unsigned* g_raw,
                                                  int* flag) {
    if (threadIdx.x < 16) sc[threadIdx.x] = 0.0f;
    if (threadIdx.x == 0) *flag = (g_raw[0] == 0x3F803F80u) ? 1 : 0;
}

// ---------------------------------------------------------------------------
// x -> x_hi (bf16) + x_lo (bf16 of residual); bf16 input -> x_lo = 0
// ---------------------------------------------------------------------------
__global__ __launch_bounds__(256) void split_x(const void* __restrict__ src,
                                               unsigned short* __restrict__ hi,
                                               unsigned short* __restrict__ lo, int n,
                                               const int* __restrict__ flagp) {
    const int flag = *flagp;
    int idx = blockIdx.x * 256 + threadIdx.x;
    int stride = gridDim.x * 256;
    if (flag) {  // bf16 in: hi = copy, lo = 0
        const uint4* s = (const uint4*)src;
        uint4* dh = (uint4*)hi;
        uint4* dl = (uint4*)lo;
        uint4 zz; zz.x = zz.y = zz.z = zz.w = 0u;
        for (int i = idx; i < n / 8; i += stride) { dh[i] = s[i]; dl[i] = zz; }
    } else {  // fp32 in
        const float4* s = (const float4*)src;
        uint2* dh = (uint2*)hi;
        uint2* dl = (uint2*)lo;
        for (int i = idx; i < n / 4; i += stride) {
            float4 v = s[i];
            unsigned h0 = f2bf(v.x), h1 = f2bf(v.y), h2 = f2bf(v.z), h3 = f2bf(v.w);
            unsigned l0 = f2bf(v.x - bf2f(h0));
            unsigned l1 = f2bf(v.y - bf2f(h1));
            unsigned l2 = f2bf(v.z - bf2f(h2));
            unsigned l3 = f2bf(v.w - bf2f(h3));
            uint2 oh; oh.x = h0 | (h1 << 16); oh.y = h2 | (h3 << 16);
            uint2 ol; ol.x = l0 | (l1 << 16); ol.y = l2 | (l3 << 16);
            dh[i] = oh;
            dl[i] = ol;
        }
    }
}

// ---------------------------------------------------------------------------
// all four small fp32 tables in one launch (exact for fp32 inputs)
// ---------------------------------------------------------------------------
__global__ __launch_bounds__(256) void to_f32_all(
    const void* __restrict__ b1, float* __restrict__ d1, int n1,
    const void* __restrict__ b2, float* __restrict__ d2, int n2,
    const void* __restrict__ b3, float* __restrict__ d3, int n3,
    const void* __restrict__ b4, float* __restrict__ d4, int n4,
    const int* __restrict__ flagp) {
    const int flag = *flagp;
    int i = blockIdx.x * 256 + threadIdx.x;
    if (flag) {
        if (i < n1) d1[i] = bf2f((unsigned)((const unsigned short*)b1)[i]);
        if (i < n2) d2[i] = bf2f((unsigned)((const unsigned short*)b2)[i]);
        if (i < n3) d3[i] = bf2f((unsigned)((const unsigned short*)b3)[i]);
        if (i < n4) d4[i] = bf2f((unsigned)((const unsigned short*)b4)[i]);
    } else {
        if (i < n1) d1[i] = ((const float*)b1)[i];
        if (i < n2) d2[i] = ((const float*)b2)[i];
        if (i < n3) d3[i] = ((const float*)b3)[i];
        if (i < n4) d4[i] = ((const float*)b4)[i];
    }
}

// ---------------------------------------------------------------------------
__global__ __launch_bounds__(256) void abs_sum_any(const void* __restrict__ w, int n,
                                                   float* __restrict__ out,
                                                   const int* __restrict__ flagp) {
    const int flag = *flagp;
    int idx = blockIdx.x * 256 + threadIdx.x;
    int stride = gridDim.x * 256;
    float s = 0.0f;
    if (flag) {
        const uint4* wv = (const uint4*)w;
        for (int c = idx; c < n / 8; c += stride) {
            uint4 v = wv[c];
            unsigned a[4] = {v.x, v.y, v.z, v.w};
#pragma unroll
            for (int j = 0; j < 4; j++)
                s += fabsf(bf2f(a[j] & 0xffffu)) + fabsf(bf2f(a[j] >> 16));
        }
    } else {
        const float4* wv = (const float4*)w;
        for (int c = idx; c < n / 4; c += stride) {
            float4 v = wv[c];
            s += fabsf(v.x) + fabsf(v.y) + fabsf(v.z) + fabsf(v.w);
        }
    }
#pragma unroll
    for (int off = 32; off; off >>= 1) s += __shfl_down(s, off);
    __shared__ float red[4];
    int lane = threadIdx.x & 63, wv_id = threadIdx.x >> 6;
    if (lane == 0) red[wv_id] = s;
    __syncthreads();
    if (threadIdx.x == 0) atomicAdd(out, red[0] + red[1] + red[2] + red[3]);
}

__global__ __launch_bounds__(64) void finalize_scale(float* sc, float inv_count) {
    if (threadIdx.x == 0) {
        sc[2] = sc[0] * inv_count;
        sc[3] = sc[1] * inv_count;
    }
}

// ---------------------------------------------------------------------------
// q = clip(rint(w / (scale + 1e-8)), -1, 1) as bf16 (exact {-1,0,+1})
// ---------------------------------------------------------------------------
__global__ __launch_bounds__(256) void quantize_any(const void* __restrict__ w,
                                                    unsigned short* __restrict__ q,
                                                    const float* __restrict__ sc, int idx,
                                                    int n, const int* __restrict__ flagp) {
    const int flag = *flagp;
    const float d = sc[idx] + 1e-8f;
    int i = blockIdx.x * 256 + threadIdx.x;
    int stride = gridDim.x * 256;
    if (flag) {
        const uint4* wv = (const uint4*)w;
        uint4* qv = (uint4*)q;
        for (; i < n / 8; i += stride) {
            uint4 v = wv[i];
            unsigned a[4] = {v.x, v.y, v.z, v.w};
            unsigned r[4];
#pragma unroll
            for (int j = 0; j < 4; j++) {
                float lo = bf2f(a[j] & 0xffffu);
                float hi = bf2f(a[j] >> 16);
                float rl = fminf(1.0f, fmaxf(-1.0f, rintf(lo / d)));
                float rh = fminf(1.0f, fmaxf(-1.0f, rintf(hi / d)));
                r[j] = f2bf(rl) | (f2bf(rh) << 16);
            }
            uint4 o;
            o.x = r[0]; o.y = r[1]; o.z = r[2]; o.w = r[3];
            qv[i] = o;
        }
    } else {
        const float4* wv = (const float4*)w;
        uint2* qv = (uint2*)q;
        for (; i < n / 4; i += stride) {
            float4 v = wv[i];
            float r0 = fminf(1.0f, fmaxf(-1.0f, rintf(v.x / d)));
            float r1 = fminf(1.0f, fmaxf(-1.0f, rintf(v.y / d)));
            float r2 = fminf(1.0f, fmaxf(-1.0f, rintf(v.z / d)));
            float r3 = fminf(1.0f, fmaxf(-1.0f, rintf(v.w / d)));
            uint2 o;
            o.x = f2bf(r0) | (f2bf(r1) << 16);
            o.y = f2bf(r2) | (f2bf(r3) << 16);
            qv[i] = o;
        }
    }
}

// ---------------------------------------------------------------------------
// C = scale * (A0[+A1] @ B^T) + bias  — m97-style: BMxBN tile, BK=64,
// global_load_lds width=16 staging, 4 waves 2x2, 16x16x32 bf16 MFMA.
// TWO: A = A0 + A1 (hi/lo split), staged together, both MFMA'd per k-step.
// KSPLIT>1: blockIdx.z picks K-range; partial kz written to C + kz*cstride.
// ---------------------------------------------------------------------------
template <int BM, int BN, bool TWO, int KSPLIT>
__global__ __launch_bounds__(256) void gemm_bt_t(const unsigned short* __restrict__ A0,
                                                 const unsigned short* __restrict__ A1,
                                                 const unsigned short* __restrict__ B,
                                                 float* __restrict__ C, size_t cstride,
                                                 const float* __restrict__ biasf,
                                                 const float* __restrict__ scp, int scidx,
                                                 int N, int K) {
    constexpr int WM = BM / 2;
    constexpr int WN = BN / 2;
    constexpr int AM = WM / 16;
    constexpr int AN = WN / 16;
    __shared__ uint4 sA[BM * 8];
    __shared__ uint4 sL[TWO ? BM * 8 : 4];
    __shared__ uint4 sB[BN * 8];
    const int tid = threadIdx.x;
    const int lane = tid & 63;
    const int wave = tid >> 6;
    const int wm = (wave >> 1) * WM;
    const int wn = (wave & 1) * WN;
    const int m0 = blockIdx.y * BM;
    const int n0 = blockIdx.x * BN;
    const int l15 = lane & 15;
    const int quad = lane >> 4;

    const int kz = (KSPLIT > 1) ? (int)blockIdx.z : 0;
    const int kper = K / KSPLIT;
    const int kbeg = kz * kper;
    const int kend = kbeg + kper;
    float* __restrict__ Cw = C + (size_t)kz * cstride;

    f32x4 acc[AM][AN];
#pragma unroll
    for (int i = 0; i < AM; i++)
#pragma unroll
        for (int j = 0; j < AN; j++) acc[i][j] = (f32x4){0.f, 0.f, 0.f, 0.f};

    const unsigned short* Abase = A0 + (size_t)m0 * K;
    const unsigned short* Lbase = TWO ? (A1 + (size_t)m0 * K) : nullptr;
    const unsigned short* Bbase = B + (size_t)n0 * K;

    for (int k0 = kbeg; k0 < kend; k0 += 64) {
#pragma unroll
        for (int i = 0; i < BM * 8 / 256; i++) {
            int s = tid + i * 256;  // slot = row*8 + chunk
            int r = s >> 3, c = s & 7;
            size_t go = (size_t)r * K + k0 + c * 8;
            gload16(Abase + go, sA + i * 256 + wave * 64);
            if (TWO) gload16(Lbase + go, sL + i * 256 + wave * 64);
        }
#pragma unroll
        for (int i = 0; i < BN * 8 / 256; i++) {
            int s = tid + i * 256;
            int r = s >> 3, c = s & 7;
            size_t go = (size_t)r * K + k0 + c * 8;
            gload16(Bbase + go, sB + i * 256 + wave * 64);
        }
        __syncthreads();
#pragma unroll
        for (int kk = 0; kk < 64; kk += 32) {
            const int jj = (kk >> 3) + quad;
            short8 ah[AM], bfr[AN];
#pragma unroll
            for (int t = 0; t < AM; t++)
                ah[t] = *(const short8*)&sA[(wm + t * 16 + l15) * 8 + jj];
#pragma unroll
            for (int t = 0; t < AN; t++)
                bfr[t] = *(const short8*)&sB[(wn + t * 16 + l15) * 8 + jj];
#pragma unroll
            for (int im = 0; im < AM; im++)
#pragma unroll
                for (int in = 0; in < AN; in++)
                    acc[im][in] = __builtin_amdgcn_mfma_f32_16x16x32_bf16(
                        ah[im], bfr[in], acc[im][in], 0, 0, 0);
            if (TWO) {
                short8 al[AM];
#pragma unroll
                for (int t = 0; t < AM; t++)
                    al[t] = *(const short8*)&sL[(wm + t * 16 + l15) * 8 + jj];
#pragma unroll
                for (int im = 0; im < AM; im++)
#pragma unroll
                    for (int in = 0; in < AN; in++)
                        acc[im][in] = __builtin_amdgcn_mfma_f32_16x16x32_bf16(
                            al[im], bfr[in], acc[im][in], 0, 0, 0);
            }
        }
        __syncthreads();
    }

    float scale = scp[scidx];
#pragma unroll
    for (int in = 0; in < AN; in++) {
        int col = n0 + wn + in * 16 + l15;
        float bv = (kz == 0) ? biasf[col] : 0.0f;
#pragma unroll
        for (int im = 0; im < AM; im++) {
            int rbase = m0 + wm + im * 16 + quad * 4;
#pragma unroll
            for (int r = 0; r < 4; r++) {
                Cw[(size_t)(rbase + r) * N + col] = scale * acc[im][in][r] + bv;
            }
        }
    }
}

// ---------------------------------------------------------------------------
// Exact k-th-largest per row. Pass0: 11-bit hist fused with key transform
// (wave-ballot aggregated atomics: keys cluster in ~20-40 sign/exp bins).
// Pass1: 11-bit hist within pass0 bucket. Then exact candidate select in the
// 22-bit bucket (fallback 10-bit pass if >256).
// hidden = (key >= kth) ? relu(z) : 0 (bf16).
// ---------------------------------------------------------------------------
__global__ __launch_bounds__(256) void topk_hidden(const float* __restrict__ z,
                                                   unsigned short* __restrict__ hidden,
                                                   int N, int k) {
    __shared__ unsigned keys[8192];
    __shared__ unsigned hist[2048];
    __shared__ unsigned wsum[4];
    __shared__ unsigned cand[256];
    __shared__ unsigned sh_want, sh_kk, sh_cnt, sh_nc, sh_kth;
    const int tid = threadIdx.x;
    const int lane = tid & 63;
    const int wv = tid >> 6;
    const size_t row = blockIdx.x;
    const float* zr = z + row * (size_t)N;

    // wave-aggregated LDS histogram add: one atomic per distinct bin per wave
    auto aggAdd = [&](unsigned bin) {
        unsigned long long todo = __ballot(1);
        while (todo) {
            int leader = __ffsll((long long)todo) - 1;
            unsigned lb = __shfl(bin, leader);
            unsigned long long eq = __ballot(bin == lb);
            if (lane == leader) atomicAdd(&hist[lb], (unsigned)__popcll(eq));
            todo &= ~eq;
        }
    };

    // suffix-scan bucket select: hist[nbins], winner updates sh_want/sh_kk/sh_cnt
    auto select_bucket = [&](int nbins, int shift) {
        const int cs = nbins >> 8;
        const int base = tid * cs;
        unsigned cv = 0;
        for (int j = 0; j < cs; j++) cv += hist[base + j];
        unsigned v = cv;
#pragma unroll
        for (int off = 1; off < 64; off <<= 1) {
            unsigned o = __shfl_down(v, off);
            if (lane + off < 64) v += o;
        }
        unsigned kk = sh_kk;  // read before the publishing barrier
        if (lane == 0) wsum[wv] = v;
        __syncthreads();
        unsigned higher = 0;
        for (int w = wv + 1; w < 4; w++) higher += wsum[w];
        unsigned incl = v + higher;
        unsigned excl = incl - cv;
        if (excl < kk && kk <= incl) {  // unique winner
            unsigned running = excl;
            for (int b = base + cs - 1; b >= base; b--) {
                unsigned h = hist[b];
                if (running + h >= kk) {
                    sh_want = sh_want | ((unsigned)b << shift);
                    sh_kk = kk - running;
                    sh_cnt = h;
                    break;
                }
                running += h;
            }
        }
        __syncthreads();
    };

    // ---- pass 0: fused load/transform/store + 11-bit hist (bits 31:21) ----
    for (int b = tid; b < 2048; b += 256) hist[b] = 0u;
    if (tid == 0) { sh_want = 0u; sh_kk = (unsigned)k; }
    __syncthreads();
    const float4* zv = (const float4*)zr;
    for (int i = tid; i < N / 4; i += 256) {
        float4 f = zv[i];
        unsigned u0 = __float_as_uint(f.x); u0 = (u0 & 0x80000000u) ? ~u0 : (u0 | 0x80000000u);
        unsigned u1 = __float_as_uint(f.y); u1 = (u1 & 0x80000000u) ? ~u1 : (u1 | 0x80000000u);
        unsigned u2 = __float_as_uint(f.z); u2 = (u2 & 0x80000000u) ? ~u2 : (u2 | 0x80000000u);
        unsigned u3 = __float_as_uint(f.w); u3 = (u3 & 0x80000000u) ? ~u3 : (u3 | 0x80000000u);
        keys[i * 4 + 0] = u0; keys[i * 4 + 1] = u1;
        keys[i * 4 + 2] = u2; keys[i * 4 + 3] = u3;
        aggAdd(u0 >> 21);
        aggAdd(u1 >> 21);
        aggAdd(u2 >> 21);
        aggAdd(u3 >> 21);
    }
    __syncthreads();
    select_bucket(2048, 21);

    // ---- pass 1: 11-bit hist (bits 20:10) within pass-0 bucket ----
    for (int b = tid; b < 2048; b += 256) hist[b] = 0u;
    __syncthreads();
    {
        const unsigned want0 = sh_want;
        for (int i = tid; i < N; i += 256) {
            unsigned u = keys[i];
            if ((u >> 21) == (want0 >> 21)) atomicAdd(&hist[(u >> 10) & 2047u], 1u);
        }
    }
    __syncthreads();
    select_bucket(2048, 10);

    // ---- finish: candidate select in the 22-bit bucket ----
    const unsigned want = sh_want;  // bits 31:10 fixed
    const unsigned cnt = sh_cnt;    // keys in that bucket
    if (tid == 0) sh_nc = 0u;
    __syncthreads();
    if (cnt <= 256u) {
        for (int i = tid; i < N; i += 256) {
            unsigned u = keys[i];
            if ((u >> 10) == (want >> 10)) {
                unsigned p = atomicAdd(&sh_nc, 1u);
                if (p < 256u) cand[p] = u;
            }
        }
        __syncthreads();
        const unsigned kk = sh_kk;
        const int nc = (int)sh_nc;
        if (tid < nc) {
            unsigned vvv = cand[tid];
            unsigned g = 0, ge = 0;
            for (int j = 0; j < nc; j++) {
                g += (cand[j] > vvv) ? 1u : 0u;
                ge += (cand[j] >= vvv) ? 1u : 0u;
            }
            if (g < kk && kk <= ge) sh_kth = vvv;  // kth order statistic (unique value)
        }
        __syncthreads();
    } else {
        // fallback: exact 10-bit pass over low bits
        for (int b = tid; b < 1024; b += 256) hist[b] = 0u;
        __syncthreads();
        for (int i = tid; i < N; i += 256) {
            unsigned u = keys[i];
            if ((u >> 10) == (want >> 10)) atomicAdd(&hist[u & 1023u], 1u);
        }
        __syncthreads();
        select_bucket(1024, 0);
        if (tid == 0) sh_kth = sh_want;
        __syncthreads();
    }
    const unsigned kth = sh_kth;

    // ---- write hidden (vectorized, 4 bf16 per uint2) ----
    unsigned short* hr = hidden + row * (size_t)N;
    uint2* hr2 = (uint2*)hr;
    for (int i = tid; i < N / 4; i += 256) {
        unsigned u0 = keys[i * 4 + 0], u1 = keys[i * 4 + 1];
        unsigned u2 = keys[i * 4 + 2], u3 = keys[i * 4 + 3];
        float f0 = (u0 & 0x80000000u) ? __uint_as_float(u0 & 0x7fffffffu) : __uint_as_float(~u0);
        float f1 = (u1 & 0x80000000u) ? __uint_as_float(u1 & 0x7fffffffu) : __uint_as_float(~u1);
        float f2 = (u2 & 0x80000000u) ? __uint_as_float(u2 & 0x7fffffffu) : __uint_as_float(~u2);
        float f3 = (u3 & 0x80000000u) ? __uint_as_float(u3 & 0x7fffffffu) : __uint_as_float(~u3);
        float h0 = (u0 >= kth) ? fmaxf(f0, 0.0f) : 0.0f;
        float h1 = (u1 >= kth) ? fmaxf(f1, 0.0f) : 0.0f;
        float h2 = (u2 >= kth) ? fmaxf(f2, 0.0f) : 0.0f;
        float h3 = (u3 >= kth) ? fmaxf(f3, 0.0f) : 0.0f;
        uint2 o;
        o.x = f2bf(h0) | (f2bf(h1) << 16);
        o.y = f2bf(h2) | (f2bf(h3) << 16);
        hr2[i] = o;
    }
}

// ---------------------------------------------------------------------------
// y = LayerNorm((x_hi+x_lo) + sum_{j<4} o_j) * gamma + beta, D=2048, FP32 out
// ---------------------------------------------------------------------------
__global__ __launch_bounds__(256) void ln_kernel(const unsigned short* __restrict__ xh,
                                                 const unsigned short* __restrict__ xl,
                                                 const float* __restrict__ o,
                                                 size_t cstride,
                                                 const float* __restrict__ gamma,
                                                 const float* __restrict__ beta,
                                                 float* __restrict__ y, int D) {
    const int tid = threadIdx.x;
    const size_t row = blockIdx.x;
    const unsigned short* xhr = xh + row * (size_t)D;
    const unsigned short* xlr = xl + row * (size_t)D;
    const float* orow = o + row * (size_t)D;
    float v[8];
    float s = 0.0f, s2 = 0.0f;
#pragma unroll
    for (int j = 0; j < 8; j++) {
        int i = tid + j * 256;
        float val = bf2f((unsigned)xhr[i]) + bf2f((unsigned)xlr[i]);
        val += orow[i] + orow[i + cstride] + orow[i + 2 * cstride] + orow[i + 3 * cstride];
        v[j] = val;
        s += val;
        s2 += val * val;
    }
#pragma unroll
    for (int off = 32; off; off >>= 1) {
        s += __shfl_down(s, off);
        s2 += __shfl_down(s2, off);
    }
    __shared__ float red[8];
    int lane = tid & 63, wv = tid >> 6;
    if (lane == 0) { red[wv] = s; red[4 + wv] = s2; }
    __syncthreads();
    float S = red[0] + red[1] + red[2] + red[3];
    float S2 = red[4] + red[5] + red[6] + red[7];
    float mu = S / (float)D;
    float var = S2 / (float)D - mu * mu;
    float inv = rsqrtf(var + 1e-5f);
#pragma unroll
    for (int j = 0; j < 8; j++) {
        int i = tid + j * 256;
        y[row * (size_t)D + i] = (v[j] - mu) * inv * gamma[i] + beta[i];
    }
}

// ---------------------------------------------------------------------------
extern "C" void kernel_launch(void* const* d_in, const int* in_sizes, int n_in,
                              void* d_out, int out_size, void* d_ws, size_t ws_size,
                              hipStream_t stream) {
    const void* x_raw = d_in[0];     // 8192x2048
    const void* Wsyn_raw = d_in[1];  // 8192x2048
    const void* bsyn_raw = d_in[2];  // 8192
    const void* Wout_raw = d_in[3];  // 2048x8192
    const void* bout_raw = d_in[4];  // 2048
    const void* gamma_raw = d_in[5]; // 2048
    const void* beta_raw = d_in[6];  // 2048
    float* out = (float*)d_out;      // FP32 output (reference output dtype)

    const int M = 8192, D = 2048, N = 8192, K1 = 2048;
    const int kTop = 819;  // int(8192 * (1 - 0.9))
    const int NW = M * D;  // 16777216 elements per weight matrix

    // ---- workspace layout ----
    // 0     : sc floats; flag int at byte 128
    // 4KB   : gamma_f (8KB) | 12KB: beta_f (8KB) | 20KB: bout_f (8KB)
    // 28KB  : bsyn_f (32KB)  -> head rounded to 64KB
    // 64KB  : x_hi 32MB | x_lo 32MB | qsyn 32MB | qout 32MB
    // chunk : z f32 (Mc x 8192); hidden bf16 (Mc x 8192)
    //         after topk, z region reused for 4 split-K partials (rows x D each)
    char* wsb = (char*)d_ws;
    float* sc = (float*)wsb;
    int* flag = (int*)(wsb + 128);
    float* gamma_f = (float*)(wsb + 4096);
    float* beta_f = (float*)(wsb + 12288);
    float* bout_f = (float*)(wsb + 20480);
    float* bsyn_f = (float*)(wsb + 28672);
    unsigned short* x_hi = (unsigned short*)(wsb + 65536);
    unsigned short* x_lo = (unsigned short*)(wsb + 65536 + 1ull * 33554432ull);
    unsigned short* qsyn = (unsigned short*)(wsb + 65536 + 2ull * 33554432ull);
    unsigned short* qout = (unsigned short*)(wsb + 65536 + 3ull * 33554432ull);
    const size_t FIXED = 65536 + 4ull * 33554432ull;  // ~128.06 MB

    const size_t per_row = (size_t)N * 4 + (size_t)N * 2;  // 49152 B
    size_t avail = (ws_size > FIXED) ? ws_size - FIXED : 0;
    long mc = (long)(avail / per_row);
    mc &= ~127L;
    if (mc > M) mc = M;
    if (mc < 128) mc = 128;
    const int Mc = (int)mc;
    char* chunk_base = wsb + FIXED;

    init_detect<<<1, 64, 0, stream>>>(sc, (const unsigned*)gamma_raw, flag);

    split_x<<<2048, 256, 0, stream>>>(x_raw, x_hi, x_lo, M * D, flag);
    to_f32_all<<<(N + 255) / 256, 256, 0, stream>>>(bsyn_raw, bsyn_f, N, bout_raw,
                                                    bout_f, D, gamma_raw, gamma_f, D,
                                                    beta_raw, beta_f, D, flag);

    abs_sum_any<<<2048, 256, 0, stream>>>(Wsyn_raw, NW, sc + 0, flag);
    abs_sum_any<<<2048, 256, 0, stream>>>(Wout_raw, NW, sc + 1, flag);
    finalize_scale<<<1, 64, 0, stream>>>(sc, 1.0f / 16777216.0f);
    quantize_any<<<2048, 256, 0, stream>>>(Wsyn_raw, qsyn, sc, 2, NW, flag);
    quantize_any<<<2048, 256, 0, stream>>>(Wout_raw, qout, sc, 3, NW, flag);

    for (int m0 = 0; m0 < M; m0 += Mc) {
        const int rows = (M - m0 < Mc) ? (M - m0) : Mc;  // multiple of 128
        float* z = (float*)chunk_base;
        unsigned short* hidden = (unsigned short*)(chunk_base + (size_t)Mc * N * 4);
        // split-K partials reuse z's space (z dead after topk):
        float* outf = (float*)chunk_base;                 // 4 x (rows x D)
        const size_t cstride = (size_t)rows * D;          // elements per partial

        dim3 g1(N / 128, rows / 128);
        gemm_bt_t<128, 128, true, 1><<<g1, 256, 0, stream>>>(
            x_hi + (size_t)m0 * K1, x_lo + (size_t)m0 * K1, qsyn, z, 0, bsyn_f,
            sc, 2, N, K1);

        topk_hidden<<<rows, 256, 0, stream>>>(z, hidden, N, kTop);

        dim3 g2(D / 128, rows / 128, 4);
        gemm_bt_t<128, 128, false, 4><<<g2, 256, 0, stream>>>(
            hidden, nullptr, qout, outf, cstride, bout_f, sc, 3, D, N);

        ln_kernel<<<rows, 256, 0, stream>>>(x_hi + (size_t)m0 * D, x_lo + (size_t)m0 * D,
                                            outf, cstride, gamma_f, beta_f,
                                            out + (size_t)m0 * D, D);
    }
}

// Round 10
// 1742.180 us; speedup vs baseline: 1.6405x; 1.6405x over previous
//
#include <hip/hip_runtime.h>

// ---------------------------------------------------------------------------
// GenesisBlock: x(8192x2048 fp32) -> z = x @ tq(W_syn)^T (f32)
//   -> top-k(819)/row threshold, hidden = relu-masked (bf16)
//   -> out = hidden @ tq(W_out)^T -> LN(x + out) -> FP32 out
//
// R14: REVERT ballot-aggregated histogram (R13: topk 50->415us — serial
// leader loop over up-to-64 distinct bins per element; HW atomic coalescing
// was already cheaper). This file = best-known config: GEMM1 128^2 TWO
// (m97-structure, ~233us), GEMM2 128^2 split-K=4, topk 2-pass radix +
// candidate select with plain LDS atomics, LN sums 4 partials, fused
// to_f32_all, NO XCD swizzle (R12: tripled FETCH).
// ---------------------------------------------------------------------------

typedef __attribute__((ext_vector_type(8))) short short8;
typedef __attribute__((ext_vector_type(4))) float f32x4;

__device__ __forceinline__ float bf2f(unsigned h) {
    return __uint_as_float(h << 16);
}
__device__ __forceinline__ unsigned f2bf(float f) {
    unsigned u = __float_as_uint(f);
    return (u + 0x7fffu + ((u >> 16) & 1u)) >> 16;  // RNE
}

// async global->LDS, 16B per lane; lds base must be wave-uniform, lane l
// deposits at base + l*16B (linear, lane-ordered).
typedef __attribute__((address_space(1))) const void gq_void;
typedef __attribute__((address_space(3))) void ls_void;
__device__ __forceinline__ void gload16(const void* g, void* l) {
    __builtin_amdgcn_global_load_lds((gq_void*)g, (ls_void*)l, 16, 0, 0);
}

// ---------------------------------------------------------------------------
__global__ __launch_bounds__(64) void init_detect(float* sc, const unsigned* g_raw,
                                                  int* flag) {
    if (threadIdx.x < 16) sc[threadIdx.x] = 0.0f;
    if (threadIdx.x == 0) *flag = (g_raw[0] == 0x3F803F80u) ? 1 : 0;
}

// ---------------------------------------------------------------------------
// x -> x_hi (bf16) + x_lo (bf16 of residual); bf16 input -> x_lo = 0
// ---------------------------------------------------------------------------
__global__ __launch_bounds__(256) void split_x(const void* __restrict__ src,
                                               unsigned short* __restrict__ hi,
                                               unsigned short* __restrict__ lo, int n,
                                               const int* __restrict__ flagp) {
    const int flag = *flagp;
    int idx = blockIdx.x * 256 + threadIdx.x;
    int stride = gridDim.x * 256;
    if (flag) {  // bf16 in: hi = copy, lo = 0
        const uint4* s = (const uint4*)src;
        uint4* dh = (uint4*)hi;
        uint4* dl = (uint4*)lo;
        uint4 zz; zz.x = zz.y = zz.z = zz.w = 0u;
        for (int i = idx; i < n / 8; i += stride) { dh[i] = s[i]; dl[i] = zz; }
    } else {  // fp32 in
        const float4* s = (const float4*)src;
        uint2* dh = (uint2*)hi;
        uint2* dl = (uint2*)lo;
        for (int i = idx; i < n / 4; i += stride) {
            float4 v = s[i];
            unsigned h0 = f2bf(v.x), h1 = f2bf(v.y), h2 = f2bf(v.z), h3 = f2bf(v.w);
            unsigned l0 = f2bf(v.x - bf2f(h0));
            unsigned l1 = f2bf(v.y - bf2f(h1));
            unsigned l2 = f2bf(v.z - bf2f(h2));
            unsigned l3 = f2bf(v.w - bf2f(h3));
            uint2 oh; oh.x = h0 | (h1 << 16); oh.y = h2 | (h3 << 16);
            uint2 ol; ol.x = l0 | (l1 << 16); ol.y = l2 | (l3 << 16);
            dh[i] = oh;
            dl[i] = ol;
        }
    }
}

// ---------------------------------------------------------------------------
// all four small fp32 tables in one launch (exact for fp32 inputs)
// ---------------------------------------------------------------------------
__global__ __launch_bounds__(256) void to_f32_all(
    const void* __restrict__ b1, float* __restrict__ d1, int n1,
    const void* __restrict__ b2, float* __restrict__ d2, int n2,
    const void* __restrict__ b3, float* __restrict__ d3, int n3,
    const void* __restrict__ b4, float* __restrict__ d4, int n4,
    const int* __restrict__ flagp) {
    const int flag = *flagp;
    int i = blockIdx.x * 256 + threadIdx.x;
    if (flag) {
        if (i < n1) d1[i] = bf2f((unsigned)((const unsigned short*)b1)[i]);
        if (i < n2) d2[i] = bf2f((unsigned)((const unsigned short*)b2)[i]);
        if (i < n3) d3[i] = bf2f((unsigned)((const unsigned short*)b3)[i]);
        if (i < n4) d4[i] = bf2f((unsigned)((const unsigned short*)b4)[i]);
    } else {
        if (i < n1) d1[i] = ((const float*)b1)[i];
        if (i < n2) d2[i] = ((const float*)b2)[i];
        if (i < n3) d3[i] = ((const float*)b3)[i];
        if (i < n4) d4[i] = ((const float*)b4)[i];
    }
}

// ---------------------------------------------------------------------------
__global__ __launch_bounds__(256) void abs_sum_any(const void* __restrict__ w, int n,
                                                   float* __restrict__ out,
                                                   const int* __restrict__ flagp) {
    const int flag = *flagp;
    int idx = blockIdx.x * 256 + threadIdx.x;
    int stride = gridDim.x * 256;
    float s = 0.0f;
    if (flag) {
        const uint4* wv = (const uint4*)w;
        for (int c = idx; c < n / 8; c += stride) {
            uint4 v = wv[c];
            unsigned a[4] = {v.x, v.y, v.z, v.w};
#pragma unroll
            for (int j = 0; j < 4; j++)
                s += fabsf(bf2f(a[j] & 0xffffu)) + fabsf(bf2f(a[j] >> 16));
        }
    } else {
        const float4* wv = (const float4*)w;
        for (int c = idx; c < n / 4; c += stride) {
            float4 v = wv[c];
            s += fabsf(v.x) + fabsf(v.y) + fabsf(v.z) + fabsf(v.w);
        }
    }
#pragma unroll
    for (int off = 32; off; off >>= 1) s += __shfl_down(s, off);
    __shared__ float red[4];
    int lane = threadIdx.x & 63, wv_id = threadIdx.x >> 6;
    if (lane == 0) red[wv_id] = s;
    __syncthreads();
    if (threadIdx.x == 0) atomicAdd(out, red[0] + red[1] + red[2] + red[3]);
}

__global__ __launch_bounds__(64) void finalize_scale(float* sc, float inv_count) {
    if (threadIdx.x == 0) {
        sc[2] = sc[0] * inv_count;
        sc[3] = sc[1] * inv_count;
    }
}

// ---------------------------------------------------------------------------
// q = clip(rint(w / (scale + 1e-8)), -1, 1) as bf16 (exact {-1,0,+1})
// ---------------------------------------------------------------------------
__global__ __launch_bounds__(256) void quantize_any(const void* __restrict__ w,
                                                    unsigned short* __restrict__ q,
                                                    const float* __restrict__ sc, int idx,
                                                    int n, const int* __restrict__ flagp) {
    const int flag = *flagp;
    const float d = sc[idx] + 1e-8f;
    int i = blockIdx.x * 256 + threadIdx.x;
    int stride = gridDim.x * 256;
    if (flag) {
        const uint4* wv = (const uint4*)w;
        uint4* qv = (uint4*)q;
        for (; i < n / 8; i += stride) {
            uint4 v = wv[i];
            unsigned a[4] = {v.x, v.y, v.z, v.w};
            unsigned r[4];
#pragma unroll
            for (int j = 0; j < 4; j++) {
                float lo = bf2f(a[j] & 0xffffu);
                float hi = bf2f(a[j] >> 16);
                float rl = fminf(1.0f, fmaxf(-1.0f, rintf(lo / d)));
                float rh = fminf(1.0f, fmaxf(-1.0f, rintf(hi / d)));
                r[j] = f2bf(rl) | (f2bf(rh) << 16);
            }
            uint4 o;
            o.x = r[0]; o.y = r[1]; o.z = r[2]; o.w = r[3];
            qv[i] = o;
        }
    } else {
        const float4* wv = (const float4*)w;
        uint2* qv = (uint2*)q;
        for (; i < n / 4; i += stride) {
            float4 v = wv[i];
            float r0 = fminf(1.0f, fmaxf(-1.0f, rintf(v.x / d)));
            float r1 = fminf(1.0f, fmaxf(-1.0f, rintf(v.y / d)));
            float r2 = fminf(1.0f, fmaxf(-1.0f, rintf(v.z / d)));
            float r3 = fminf(1.0f, fmaxf(-1.0f, rintf(v.w / d)));
            uint2 o;
            o.x = f2bf(r0) | (f2bf(r1) << 16);
            o.y = f2bf(r2) | (f2bf(r3) << 16);
            qv[i] = o;
        }
    }
}

// ---------------------------------------------------------------------------
// C = scale * (A0[+A1] @ B^T) + bias  — m97-style: BMxBN tile, BK=64,
// global_load_lds width=16 staging, 4 waves 2x2, 16x16x32 bf16 MFMA.
// TWO: A = A0 + A1 (hi/lo split), staged together, both MFMA'd per k-step.
// KSPLIT>1: blockIdx.z picks K-range; partial kz written to C + kz*cstride.
// ---------------------------------------------------------------------------
template <int BM, int BN, bool TWO, int KSPLIT>
__global__ __launch_bounds__(256) void gemm_bt_t(const unsigned short* __restrict__ A0,
                                                 const unsigned short* __restrict__ A1,
                                                 const unsigned short* __restrict__ B,
                                                 float* __restrict__ C, size_t cstride,
                                                 const float* __restrict__ biasf,
                                                 const float* __restrict__ scp, int scidx,
                                                 int N, int K) {
    constexpr int WM = BM / 2;
    constexpr int WN = BN / 2;
    constexpr int AM = WM / 16;
    constexpr int AN = WN / 16;
    __shared__ uint4 sA[BM * 8];
    __shared__ uint4 sL[TWO ? BM * 8 : 4];
    __shared__ uint4 sB[BN * 8];
    const int tid = threadIdx.x;
    const int lane = tid & 63;
    const int wave = tid >> 6;
    const int wm = (wave >> 1) * WM;
    const int wn = (wave & 1) * WN;
    const int m0 = blockIdx.y * BM;
    const int n0 = blockIdx.x * BN;
    const int l15 = lane & 15;
    const int quad = lane >> 4;

    const int kz = (KSPLIT > 1) ? (int)blockIdx.z : 0;
    const int kper = K / KSPLIT;
    const int kbeg = kz * kper;
    const int kend = kbeg + kper;
    float* __restrict__ Cw = C + (size_t)kz * cstride;

    f32x4 acc[AM][AN];
#pragma unroll
    for (int i = 0; i < AM; i++)
#pragma unroll
        for (int j = 0; j < AN; j++) acc[i][j] = (f32x4){0.f, 0.f, 0.f, 0.f};

    const unsigned short* Abase = A0 + (size_t)m0 * K;
    const unsigned short* Lbase = TWO ? (A1 + (size_t)m0 * K) : nullptr;
    const unsigned short* Bbase = B + (size_t)n0 * K;

    for (int k0 = kbeg; k0 < kend; k0 += 64) {
#pragma unroll
        for (int i = 0; i < BM * 8 / 256; i++) {
            int s = tid + i * 256;  // slot = row*8 + chunk
            int r = s >> 3, c = s & 7;
            size_t go = (size_t)r * K + k0 + c * 8;
            gload16(Abase + go, sA + i * 256 + wave * 64);
            if (TWO) gload16(Lbase + go, sL + i * 256 + wave * 64);
        }
#pragma unroll
        for (int i = 0; i < BN * 8 / 256; i++) {
            int s = tid + i * 256;
            int r = s >> 3, c = s & 7;
            size_t go = (size_t)r * K + k0 + c * 8;
            gload16(Bbase + go, sB + i * 256 + wave * 64);
        }
        __syncthreads();
#pragma unroll
        for (int kk = 0; kk < 64; kk += 32) {
            const int jj = (kk >> 3) + quad;
            short8 ah[AM], bfr[AN];
#pragma unroll
            for (int t = 0; t < AM; t++)
                ah[t] = *(const short8*)&sA[(wm + t * 16 + l15) * 8 + jj];
#pragma unroll
            for (int t = 0; t < AN; t++)
                bfr[t] = *(const short8*)&sB[(wn + t * 16 + l15) * 8 + jj];
#pragma unroll
            for (int im = 0; im < AM; im++)
#pragma unroll
                for (int in = 0; in < AN; in++)
                    acc[im][in] = __builtin_amdgcn_mfma_f32_16x16x32_bf16(
                        ah[im], bfr[in], acc[im][in], 0, 0, 0);
            if (TWO) {
                short8 al[AM];
#pragma unroll
                for (int t = 0; t < AM; t++)
                    al[t] = *(const short8*)&sL[(wm + t * 16 + l15) * 8 + jj];
#pragma unroll
                for (int im = 0; im < AM; im++)
#pragma unroll
                    for (int in = 0; in < AN; in++)
                        acc[im][in] = __builtin_amdgcn_mfma_f32_16x16x32_bf16(
                            al[im], bfr[in], acc[im][in], 0, 0, 0);
            }
        }
        __syncthreads();
    }

    float scale = scp[scidx];
#pragma unroll
    for (int in = 0; in < AN; in++) {
        int col = n0 + wn + in * 16 + l15;
        float bv = (kz == 0) ? biasf[col] : 0.0f;
#pragma unroll
        for (int im = 0; im < AM; im++) {
            int rbase = m0 + wm + im * 16 + quad * 4;
#pragma unroll
            for (int r = 0; r < 4; r++) {
                Cw[(size_t)(rbase + r) * N + col] = scale * acc[im][in][r] + bv;
            }
        }
    }
}

// ---------------------------------------------------------------------------
// Exact k-th-largest per row. Pass0: 11-bit hist fused with key transform
// (plain LDS atomics — R13's ballot-aggregation was 8x slower).
// Pass1: 11-bit hist within pass0 bucket. Then exact candidate select in the
// 22-bit bucket (fallback 10-bit pass if >256).
// hidden = (key >= kth) ? relu(z) : 0 (bf16).
// ---------------------------------------------------------------------------
__global__ __launch_bounds__(256) void topk_hidden(const float* __restrict__ z,
                                                   unsigned short* __restrict__ hidden,
                                                   int N, int k) {
    __shared__ unsigned keys[8192];
    __shared__ unsigned hist[2048];
    __shared__ unsigned wsum[4];
    __shared__ unsigned cand[256];
    __shared__ unsigned sh_want, sh_kk, sh_cnt, sh_nc, sh_kth;
    const int tid = threadIdx.x;
    const int lane = tid & 63;
    const int wv = tid >> 6;
    const size_t row = blockIdx.x;
    const float* zr = z + row * (size_t)N;

    // suffix-scan bucket select: hist[nbins], winner updates sh_want/sh_kk/sh_cnt
    auto select_bucket = [&](int nbins, int shift) {
        const int cs = nbins >> 8;
        const int base = tid * cs;
        unsigned cv = 0;
        for (int j = 0; j < cs; j++) cv += hist[base + j];
        unsigned v = cv;
#pragma unroll
        for (int off = 1; off < 64; off <<= 1) {
            unsigned o = __shfl_down(v, off);
            if (lane + off < 64) v += o;
        }
        unsigned kk = sh_kk;  // read before the publishing barrier
        if (lane == 0) wsum[wv] = v;
        __syncthreads();
        unsigned higher = 0;
        for (int w = wv + 1; w < 4; w++) higher += wsum[w];
        unsigned incl = v + higher;
        unsigned excl = incl - cv;
        if (excl < kk && kk <= incl) {  // unique winner
            unsigned running = excl;
            for (int b = base + cs - 1; b >= base; b--) {
                unsigned h = hist[b];
                if (running + h >= kk) {
                    sh_want = sh_want | ((unsigned)b << shift);
                    sh_kk = kk - running;
                    sh_cnt = h;
                    break;
                }
                running += h;
            }
        }
        __syncthreads();
    };

    // ---- pass 0: fused load/transform/store + 11-bit hist (bits 31:21) ----
    for (int b = tid; b < 2048; b += 256) hist[b] = 0u;
    if (tid == 0) { sh_want = 0u; sh_kk = (unsigned)k; }
    __syncthreads();
    const float4* zv = (const float4*)zr;
    for (int i = tid; i < N / 4; i += 256) {
        float4 f = zv[i];
        unsigned u0 = __float_as_uint(f.x); u0 = (u0 & 0x80000000u) ? ~u0 : (u0 | 0x80000000u);
        unsigned u1 = __float_as_uint(f.y); u1 = (u1 & 0x80000000u) ? ~u1 : (u1 | 0x80000000u);
        unsigned u2 = __float_as_uint(f.z); u2 = (u2 & 0x80000000u) ? ~u2 : (u2 | 0x80000000u);
        unsigned u3 = __float_as_uint(f.w); u3 = (u3 & 0x80000000u) ? ~u3 : (u3 | 0x80000000u);
        keys[i * 4 + 0] = u0; keys[i * 4 + 1] = u1;
        keys[i * 4 + 2] = u2; keys[i * 4 + 3] = u3;
        atomicAdd(&hist[u0 >> 21], 1u);
        atomicAdd(&hist[u1 >> 21], 1u);
        atomicAdd(&hist[u2 >> 21], 1u);
        atomicAdd(&hist[u3 >> 21], 1u);
    }
    __syncthreads();
    select_bucket(2048, 21);

    // ---- pass 1: 11-bit hist (bits 20:10) within pass-0 bucket ----
    for (int b = tid; b < 2048; b += 256) hist[b] = 0u;
    __syncthreads();
    {
        const unsigned want0 = sh_want;
        for (int i = tid; i < N; i += 256) {
            unsigned u = keys[i];
            if ((u >> 21) == (want0 >> 21)) atomicAdd(&hist[(u >> 10) & 2047u], 1u);
        }
    }
    __syncthreads();
    select_bucket(2048, 10);

    // ---- finish: candidate select in the 22-bit bucket ----
    const unsigned want = sh_want;  // bits 31:10 fixed
    const unsigned cnt = sh_cnt;    // keys in that bucket
    if (tid == 0) sh_nc = 0u;
    __syncthreads();
    if (cnt <= 256u) {
        for (int i = tid; i < N; i += 256) {
            unsigned u = keys[i];
            if ((u >> 10) == (want >> 10)) {
                unsigned p = atomicAdd(&sh_nc, 1u);
                if (p < 256u) cand[p] = u;
            }
        }
        __syncthreads();
        const unsigned kk = sh_kk;
        const int nc = (int)sh_nc;
        if (tid < nc) {
            unsigned vvv = cand[tid];
            unsigned g = 0, ge = 0;
            for (int j = 0; j < nc; j++) {
                g += (cand[j] > vvv) ? 1u : 0u;
                ge += (cand[j] >= vvv) ? 1u : 0u;
            }
            if (g < kk && kk <= ge) sh_kth = vvv;  // kth order statistic (unique value)
        }
        __syncthreads();
    } else {
        // fallback: exact 10-bit pass over low bits
        for (int b = tid; b < 1024; b += 256) hist[b] = 0u;
        __syncthreads();
        for (int i = tid; i < N; i += 256) {
            unsigned u = keys[i];
            if ((u >> 10) == (want >> 10)) atomicAdd(&hist[u & 1023u], 1u);
        }
        __syncthreads();
        select_bucket(1024, 0);
        if (tid == 0) sh_kth = sh_want;
        __syncthreads();
    }
    const unsigned kth = sh_kth;

    // ---- write hidden (vectorized, 4 bf16 per uint2) ----
    unsigned short* hr = hidden + row * (size_t)N;
    uint2* hr2 = (uint2*)hr;
    for (int i = tid; i < N / 4; i += 256) {
        unsigned u0 = keys[i * 4 + 0], u1 = keys[i * 4 + 1];
        unsigned u2 = keys[i * 4 + 2], u3 = keys[i * 4 + 3];
        float f0 = (u0 & 0x80000000u) ? __uint_as_float(u0 & 0x7fffffffu) : __uint_as_float(~u0);
        float f1 = (u1 & 0x80000000u) ? __uint_as_float(u1 & 0x7fffffffu) : __uint_as_float(~u1);
        float f2 = (u2 & 0x80000000u) ? __uint_as_float(u2 & 0x7fffffffu) : __uint_as_float(~u2);
        float f3 = (u3 & 0x80000000u) ? __uint_as_float(u3 & 0x7fffffffu) : __uint_as_float(~u3);
        float h0 = (u0 >= kth) ? fmaxf(f0, 0.0f) : 0.0f;
        float h1 = (u1 >= kth) ? fmaxf(f1, 0.0f) : 0.0f;
        float h2 = (u2 >= kth) ? fmaxf(f2, 0.0f) : 0.0f;
        float h3 = (u3 >= kth) ? fmaxf(f3, 0.0f) : 0.0f;
        uint2 o;
        o.x = f2bf(h0) | (f2bf(h1) << 16);
        o.y = f2bf(h2) | (f2bf(h3) << 16);
        hr2[i] = o;
    }
}

// ---------------------------------------------------------------------------
// y = LayerNorm((x_hi+x_lo) + sum_{j<4} o_j) * gamma + beta, D=2048, FP32 out
// ---------------------------------------------------------------------------
__global__ __launch_bounds__(256) void ln_kernel(const unsigned short* __restrict__ xh,
                                                 const unsigned short* __restrict__ xl,
                                                 const float* __restrict__ o,
                                                 size_t cstride,
                                                 const float* __restrict__ gamma,
                                                 const float* __restrict__ beta,
                                                 float* __restrict__ y, int D) {
    const int tid = threadIdx.x;
    const size_t row = blockIdx.x;
    const unsigned short* xhr = xh + row * (size_t)D;
    const unsigned short* xlr = xl + row * (size_t)D;
    const float* orow = o + row * (size_t)D;
    float v[8];
    float s = 0.0f, s2 = 0.0f;
#pragma unroll
    for (int j = 0; j < 8; j++) {
        int i = tid + j * 256;
        float val = bf2f((unsigned)xhr[i]) + bf2f((unsigned)xlr[i]);
        val += orow[i] + orow[i + cstride] + orow[i + 2 * cstride] + orow[i + 3 * cstride];
        v[j] = val;
        s += val;
        s2 += val * val;
    }
#pragma unroll
    for (int off = 32; off; off >>= 1) {
        s += __shfl_down(s, off);
        s2 += __shfl_down(s2, off);
    }
    __shared__ float red[8];
    int lane = tid & 63, wv = tid >> 6;
    if (lane == 0) { red[wv] = s; red[4 + wv] = s2; }
    __syncthreads();
    float S = red[0] + red[1] + red[2] + red[3];
    float S2 = red[4] + red[5] + red[6] + red[7];
    float mu = S / (float)D;
    float var = S2 / (float)D - mu * mu;
    float inv = rsqrtf(var + 1e-5f);
#pragma unroll
    for (int j = 0; j < 8; j++) {
        int i = tid + j * 256;
        y[row * (size_t)D + i] = (v[j] - mu) * inv * gamma[i] + beta[i];
    }
}

// ---------------------------------------------------------------------------
extern "C" void kernel_launch(void* const* d_in, const int* in_sizes, int n_in,
                              void* d_out, int out_size, void* d_ws, size_t ws_size,
                              hipStream_t stream) {
    const void* x_raw = d_in[0];     // 8192x2048
    const void* Wsyn_raw = d_in[1];  // 8192x2048
    const void* bsyn_raw = d_in[2];  // 8192
    const void* Wout_raw = d_in[3];  // 2048x8192
    const void* bout_raw = d_in[4];  // 2048
    const void* gamma_raw = d_in[5]; // 2048
    const void* beta_raw = d_in[6];  // 2048
    float* out = (float*)d_out;      // FP32 output (reference output dtype)

    const int M = 8192, D = 2048, N = 8192, K1 = 2048;
    const int kTop = 819;  // int(8192 * (1 - 0.9))
    const int NW = M * D;  // 16777216 elements per weight matrix

    // ---- workspace layout ----
    // 0     : sc floats; flag int at byte 128
    // 4KB   : gamma_f (8KB) | 12KB: beta_f (8KB) | 20KB: bout_f (8KB)
    // 28KB  : bsyn_f (32KB)  -> head rounded to 64KB
    // 64KB  : x_hi 32MB | x_lo 32MB | qsyn 32MB | qout 32MB
    // chunk : z f32 (Mc x 8192); hidden bf16 (Mc x 8192)
    //         after topk, z region reused for 4 split-K partials (rows x D each)
    char* wsb = (char*)d_ws;
    float* sc = (float*)wsb;
    int* flag = (int*)(wsb + 128);
    float* gamma_f = (float*)(wsb + 4096);
    float* beta_f = (float*)(wsb + 12288);
    float* bout_f = (float*)(wsb + 20480);
    float* bsyn_f = (float*)(wsb + 28672);
    unsigned short* x_hi = (unsigned short*)(wsb + 65536);
    unsigned short* x_lo = (unsigned short*)(wsb + 65536 + 1ull * 33554432ull);
    unsigned short* qsyn = (unsigned short*)(wsb + 65536 + 2ull * 33554432ull);
    unsigned short* qout = (unsigned short*)(wsb + 65536 + 3ull * 33554432ull);
    const size_t FIXED = 65536 + 4ull * 33554432ull;  // ~128.06 MB

    const size_t per_row = (size_t)N * 4 + (size_t)N * 2;  // 49152 B
    size_t avail = (ws_size > FIXED) ? ws_size - FIXED : 0;
    long mc = (long)(avail / per_row);
    mc &= ~127L;
    if (mc > M) mc = M;
    if (mc < 128) mc = 128;
    const int Mc = (int)mc;
    char* chunk_base = wsb + FIXED;

    init_detect<<<1, 64, 0, stream>>>(sc, (const unsigned*)gamma_raw, flag);

    split_x<<<2048, 256, 0, stream>>>(x_raw, x_hi, x_lo, M * D, flag);
    to_f32_all<<<(N + 255) / 256, 256, 0, stream>>>(bsyn_raw, bsyn_f, N, bout_raw,
                                                    bout_f, D, gamma_raw, gamma_f, D,
                                                    beta_raw, beta_f, D, flag);

    abs_sum_any<<<2048, 256, 0, stream>>>(Wsyn_raw, NW, sc + 0, flag);
    abs_sum_any<<<2048, 256, 0, stream>>>(Wout_raw, NW, sc + 1, flag);
    finalize_scale<<<1, 64, 0, stream>>>(sc, 1.0f / 16777216.0f);
    quantize_any<<<2048, 256, 0, stream>>>(Wsyn_raw, qsyn, sc, 2, NW, flag);
    quantize_any<<<2048, 256, 0, stream>>>(Wout_raw, qout, sc, 3, NW, flag);

    for (int m0 = 0; m0 < M; m0 += Mc) {
        const int rows = (M - m0 < Mc) ? (M - m0) : Mc;  // multiple of 128
        float* z = (float*)chunk_base;
        unsigned short* hidden = (unsigned short*)(chunk_base + (size_t)Mc * N * 4);
        // split-K partials reuse z's space (z dead after topk):
        float* outf = (float*)chunk_base;                 // 4 x (rows x D)
        const size_t cstride = (size_t)rows * D;          // elements per partial

        dim3 g1(N / 128, rows / 128);
        gemm_bt_t<128, 128, true, 1><<<g1, 256, 0, stream>>>(
            x_hi + (size_t)m0 * K1, x_lo + (size_t)m0 * K1, qsyn, z, 0, bsyn_f,
            sc, 2, N, K1);

        topk_hidden<<<rows, 256, 0, stream>>>(z, hidden, N, kTop);

        dim3 g2(D / 128, rows / 128, 4);
        gemm_bt_t<128, 128, false, 4><<<g2, 256, 0, stream>>>(
            hidden, nullptr, qout, outf, cstride, bout_f, sc, 3, D, N);

        ln_kernel<<<rows, 256, 0, stream>>>(x_hi + (size_t)m0 * D, x_lo + (size_t)m0 * D,
                                            outf, cstride, gamma_f, beta_f,
                                            out + (size_t)m0 * D, D);
    }
}